// Round 6
// baseline (23.648 us; speedup 1.0000x reference)
//
#include <hip/hip_runtime.h>
#include <hip/hip_fp16.h>

// Problem constants (reference: B=4, N=512, F_IN=F_OUT=128)
constexpr int B_   = 4;
constexpr int N_   = 512;
constexpr int F    = 128;
constexpr int R2B  = 8;     // rows per block, kernel 2
constexpr int LSTW = 520;   // neighbor-list stride (512 + pad)
constexpr int XPAD = 136;   // LDS row stride in bf16 (128 + 8 -> 2-way bank alias, free)

typedef short bf16x8 __attribute__((ext_vector_type(8)));   // 8 bf16 = 4 VGPR
typedef float f32x4  __attribute__((ext_vector_type(4)));

__device__ inline ushort f2bf(float f) {      // RNE f32 -> bf16 bits
    union { float f; uint u; } v; v.f = f;
    const uint b = v.u + (0x7FFFu + ((v.u >> 16) & 1u));
    return (ushort)(b >> 16);
}

// ---------------------------------------------------------------------------
// Kernel 1 (512 blocks x 128 threads): block = (M-tile of 16 rows, N-quarter)
//   - ballot-compact 4 of the tile's adj rows -> lstG/cntG (sentinel pads)
//   - MFMA bf16: [xi | xj | xu] = x @ [Wi | Wj | Wupd[0:F]]  (N = 384)
//     per block: 6 16-wide N-tiles, 3 per wave, K=128 (4 MFMA each)
//   - xi += b_msg (f32 out), xj -> fp16, xu f32
// ---------------------------------------------------------------------------
__global__ __launch_bounds__(128) void k_pre(
    const float* __restrict__ x,
    const float* __restrict__ adj,
    const float* __restrict__ Wmsg,
    const float* __restrict__ bmsg,
    const float* __restrict__ Wupd,
    float*  __restrict__ xi,
    __half* __restrict__ xjH,
    float*  __restrict__ xu,
    int*    __restrict__ lstG,
    int*    __restrict__ cntG)
{
    __shared__ __align__(16) ushort xsb[16][XPAD];   // x-tile, bf16

    const int t    = threadIdx.x;
    const int lane = t & 63;
    const int wv   = t >> 6;               // wave 0..1
    const int mt   = blockIdx.x >> 2;      // M-tile (16 rows)
    const int nq   = blockIdx.x & 3;       // N-quarter (6 of 24 N-tiles)
    const int r0   = mt * 16;
    const int b    = r0 >> 9;
    const int i0   = r0 & (N_ - 1);
    const int PADJ = B_ * N_ - b * N_;     // sentinel row index (batch-relative)

    // sentinel xj row: relu(xi - 60000) == 0
    if (blockIdx.x == 0) xjH[(size_t)(B_ * N_) * F + t] = __float2half(-60000.f);

    // ---- stage x-tile as bf16 (16 rows x 128)
    {
        const int row = t >> 3, c16 = (t & 7) * 16;
        const float* src = &x[(size_t)(r0 + row) * F + c16];
        #pragma unroll
        for (int hh = 0; hh < 2; ++hh) {
            const float4 p0 = *reinterpret_cast<const float4*>(src + hh * 8);
            const float4 p1 = *reinterpret_cast<const float4*>(src + hh * 8 + 4);
            uint4 pk;
            pk.x = (uint)f2bf(p0.x) | ((uint)f2bf(p0.y) << 16);
            pk.y = (uint)f2bf(p0.z) | ((uint)f2bf(p0.w) << 16);
            pk.z = (uint)f2bf(p1.x) | ((uint)f2bf(p1.y) << 16);
            pk.w = (uint)f2bf(p1.z) | ((uint)f2bf(p1.w) << 16);
            *reinterpret_cast<uint4*>(&xsb[row][c16 + hh * 8]) = pk;
        }
    }

    // ---- ballot compaction: this block owns rows nq*4 .. nq*4+3 of the tile
    #pragma unroll
    for (int p = 0; p < 2; ++p) {
        const int lr = nq * 4 + wv * 2 + p;
        const float* arow = adj + (size_t)(b * N_ + i0 + lr) * N_;
        int* lrow = lstG + (size_t)(r0 + lr) * LSTW;
        int base = 0;
        #pragma unroll
        for (int s = 0; s < 8; ++s) {
            const float a = arow[s * 64 + lane];
            const unsigned long long m = __ballot(a != 0.f);
            const int off = __popcll(m & ((1ull << lane) - 1ull));
            if (a != 0.f) lrow[base + off] = s * 64 + lane;
            base += __popcll(m);
        }
        const int np = (base + 7) & ~7;
        if (lane < np - base) lrow[base + lane] = PADJ;   // sentinel pads
        if (lane == 0) cntG[r0 + lr] = np;
    }
    __syncthreads();

    // ---- A-fragments: full K=128 (4 frags of 8 contiguous k's per lane)
    const int arow = lane & 15, kg = lane >> 4;
    bf16x8 afr[4];
    #pragma unroll
    for (int ks = 0; ks < 4; ++ks)
        afr[ks] = *reinterpret_cast<const bf16x8*>(&xsb[arow][ks * 32 + kg * 8]);

    // ---- 3 N-tiles per wave: load B (f32 -> bf16), 4 MFMA, store
    const int col = lane & 15;
    #pragma unroll
    for (int j = 0; j < 3; ++j) {
        const int nt = nq * 6 + wv * 3 + j;            // 0..23
        const int o  = (nt & 7) * 16 + col;            // column within 128-wide output
        const float* wsrc = (nt < 8) ? Wmsg
                          : (nt < 16) ? (Wmsg + (size_t)F * F)
                          : Wupd;
        f32x4 acc = {0.f, 0.f, 0.f, 0.f};
        #pragma unroll
        for (int ks = 0; ks < 4; ++ks) {
            const int k0 = ks * 32 + kg * 8;
            bf16x8 bfr;
            #pragma unroll
            for (int e = 0; e < 8; ++e)
                bfr[e] = (short)f2bf(wsrc[(size_t)(k0 + e) * F + o]);
            acc = __builtin_amdgcn_mfma_f32_16x16x32_bf16(afr[ks], bfr, acc, 0, 0, 0);
        }
        const int orow = r0 + (lane >> 4) * 4;
        if (nt < 8) {
            const float bm = bmsg[o];
            #pragma unroll
            for (int g = 0; g < 4; ++g)
                xi[(size_t)(orow + g) * F + o] = acc[g] + bm;
        } else if (nt < 16) {
            #pragma unroll
            for (int g = 0; g < 4; ++g)
                xjH[(size_t)(orow + g) * F + o] = __float2half(acc[g]);
        } else {
            #pragma unroll
            for (int g = 0; g < 4; ++g)
                xu[(size_t)(orow + g) * F + o] = acc[g];
        }
    }
}

// ---------------------------------------------------------------------------
// Kernel 2 (256 blocks x 512 threads): unchanged from R5 (attribution)
// ---------------------------------------------------------------------------
__global__ __launch_bounds__(512) void k_agg(
    const int*    __restrict__ lstG,
    const int*    __restrict__ cntG,
    const float*  __restrict__ xi,
    const __half* __restrict__ xjH,
    const float*  __restrict__ xu,
    const float*  __restrict__ Wupd,
    const float*  __restrict__ bupd,
    float* __restrict__ out)
{
    __shared__ __align__(16) float agg[R2B][F];

    const int t    = threadIdx.x;
    const int lane = t & 63;
    const int w    = t >> 6;
    const int o    = t & 127;
    const int gg   = t >> 7;
    const int r0   = blockIdx.x * R2B;
    const int b    = r0 >> 9;

    {
        const __half* xjb = xjH + (size_t)b * N_ * F;
        const float2 xir2 = *reinterpret_cast<const float2*>(
            &xi[(size_t)(r0 + w) * F + 2 * lane]);
        const int np = cntG[r0 + w];
        const int* lrow = lstG + (size_t)(r0 + w) * LSTW;
        float2 acc = {0.f, 0.f};

        if (np > 0) {
            int4 a = *reinterpret_cast<const int4*>(&lrow[0]);
            int4 c = *reinterpret_cast<const int4*>(&lrow[4]);
            for (int k = 0; k < np; k += 8) {
                const int4 an = *reinterpret_cast<const int4*>(&lrow[k + 8]);
                const int4 cn = *reinterpret_cast<const int4*>(&lrow[k + 12]);
                const float2 v0 = __half22float2(*reinterpret_cast<const __half2*>(&xjb[(size_t)a.x * F + 2 * lane]));
                const float2 v1 = __half22float2(*reinterpret_cast<const __half2*>(&xjb[(size_t)a.y * F + 2 * lane]));
                const float2 v2 = __half22float2(*reinterpret_cast<const __half2*>(&xjb[(size_t)a.z * F + 2 * lane]));
                const float2 v3 = __half22float2(*reinterpret_cast<const __half2*>(&xjb[(size_t)a.w * F + 2 * lane]));
                const float2 v4 = __half22float2(*reinterpret_cast<const __half2*>(&xjb[(size_t)c.x * F + 2 * lane]));
                const float2 v5 = __half22float2(*reinterpret_cast<const __half2*>(&xjb[(size_t)c.y * F + 2 * lane]));
                const float2 v6 = __half22float2(*reinterpret_cast<const __half2*>(&xjb[(size_t)c.z * F + 2 * lane]));
                const float2 v7 = __half22float2(*reinterpret_cast<const __half2*>(&xjb[(size_t)c.w * F + 2 * lane]));
                acc.x += fmaxf(xir2.x + v0.x, 0.f);  acc.y += fmaxf(xir2.y + v0.y, 0.f);
                acc.x += fmaxf(xir2.x + v1.x, 0.f);  acc.y += fmaxf(xir2.y + v1.y, 0.f);
                acc.x += fmaxf(xir2.x + v2.x, 0.f);  acc.y += fmaxf(xir2.y + v2.y, 0.f);
                acc.x += fmaxf(xir2.x + v3.x, 0.f);  acc.y += fmaxf(xir2.y + v3.y, 0.f);
                acc.x += fmaxf(xir2.x + v4.x, 0.f);  acc.y += fmaxf(xir2.y + v4.y, 0.f);
                acc.x += fmaxf(xir2.x + v5.x, 0.f);  acc.y += fmaxf(xir2.y + v5.y, 0.f);
                acc.x += fmaxf(xir2.x + v6.x, 0.f);  acc.y += fmaxf(xir2.y + v6.y, 0.f);
                acc.x += fmaxf(xir2.x + v7.x, 0.f);  acc.y += fmaxf(xir2.y + v7.y, 0.f);
                a = an; c = cn;
            }
        }
        *reinterpret_cast<float2*>(&agg[w][2 * lane]) = acc;
    }
    __syncthreads();

    float res0 = 0.f, res1 = 0.f;
    const int rA = 2 * gg, rB = 2 * gg + 1;
    #pragma unroll
    for (int k = 0; k < F; k += 4) {
        const float4 a0 = *reinterpret_cast<const float4*>(&agg[rA][k]);
        const float4 a1 = *reinterpret_cast<const float4*>(&agg[rB][k]);
        #pragma unroll
        for (int u = 0; u < 4; ++u) {
            const float wv = Wupd[(size_t)(F + k + u) * F + o];
            res0 = fmaf(reinterpret_cast<const float*>(&a0)[u], wv, res0);
            res1 = fmaf(reinterpret_cast<const float*>(&a1)[u], wv, res1);
        }
    }
    const float bu = bupd[o];
    out[(size_t)(r0 + rA) * F + o] =
        fmaxf(res0 + xu[(size_t)(r0 + rA) * F + o] + bu, 0.f);
    out[(size_t)(r0 + rB) * F + o] =
        fmaxf(res1 + xu[(size_t)(r0 + rB) * F + o] + bu, 0.f);
}

// ---------------------------------------------------------------------------
extern "C" void kernel_launch(void* const* d_in, const int* in_sizes, int n_in,
                              void* d_out, int out_size, void* d_ws, size_t ws_size,
                              hipStream_t stream)
{
    const float* x    = (const float*)d_in[0];
    const float* adj  = (const float*)d_in[1];
    const float* Wmsg = (const float*)d_in[2];
    const float* bmsg = (const float*)d_in[3];
    const float* Wupd = (const float*)d_in[4];
    const float* bupd = (const float*)d_in[5];
    float* out = (float*)d_out;

    const size_t rows = (size_t)B_ * N_;               // 2048
    float*  xi   = (float*)d_ws;                       // 1 MB
    float*  xu   = xi + rows * F;                      // 1 MB
    int*    lstG = (int*)(xu + rows * F);              // rows*LSTW ints
    int*    cntG = lstG + rows * LSTW;                 // rows ints
    __half* xjH  = (__half*)(cntG + rows);             // (rows+1)*F halfs

    k_pre<<<dim3((rows / 16) * 4), dim3(128), 0, stream>>>(
        x, adj, Wmsg, bmsg, Wupd, xi, xjH, xu, lstG, cntG);
    k_agg<<<dim3(rows / R2B), dim3(512), 0, stream>>>(
        lstG, cntG, xi, xjH, xu, Wupd, bupd, out);
}